// Round 19
// baseline (308.168 us; speedup 1.0000x reference)
//
#include <hip/hip_runtime.h>
#include <hip/hip_bf16.h>

#define SLEN 512
#define BATCH 256
#define NIN 300
#define KP 320
#define NG 256
#define NH 64
#define BM 128
#define BN 128
#define BK 64
#define LDP 72   // padded LDS row length (f16) -> 144B rows, 2-way (free) b128 reads
#define TC 128   // steps per chunk
#define NCH (SLEN / TC)

typedef float f32x4 __attribute__((ext_vector_type(4)));
typedef _Float16 f16x8 __attribute__((ext_vector_type(8)));
typedef _Float16 f16x4 __attribute__((ext_vector_type(4)));

// pair swap within quads via DPP quad_perm [1,0,3,2] — VALU-speed cross-lane
__device__ __forceinline__ float pair_swap(float v) {
  return __builtin_bit_cast(float,
      __builtin_amdgcn_mov_dpp(__builtin_bit_cast(int, v), 0xB1, 0xf, 0xf, true));
}

// Build Wc16[n][k] (f16, K padded to 320), bcat[n], and Wg16[col][k] = f16(W_glt[k][col]).
__global__ void prep_w(const float* __restrict__ Wpt0, const float* __restrict__ bpt0,
                       const float* __restrict__ Wpt1, const float* __restrict__ bpt1,
                       const float* __restrict__ Wglt,
                       _Float16* __restrict__ Wc16, float* __restrict__ bcat,
                       _Float16* __restrict__ Wg16) {
  int idx = blockIdx.x * 256 + threadIdx.x;
  if (idx < NG * KP) {
    int n = idx / KP, k = idx - n * KP;
    int g = n >> 6, h = n & 63;
    float w = 0.f;
    if (k < NIN) {
      if (h < 32) w = Wpt0[k * 128 + g * 32 + h];
      else        w = 0.5f * Wpt1[(k >> 1) * 128 + g * 32 + (h - 32)];
    }
    Wc16[idx] = (_Float16)w;
  }
  if (idx < NG * NH) {  // transpose W_glt (64 x 256) -> Wg16 (256 x 64), f16
    int c = idx >> 6, k = idx & 63;
    Wg16[idx] = (_Float16)Wglt[k * NG + c];
  }
  if (idx < NG) {
    int g = idx >> 6, h = idx & 63;
    bcat[idx] = (h < 32) ? bpt0[g * 32 + h] : bpt1[g * 32 + h - 32];
  }
}

// ---------------- shared device bodies (used by standalone + fused) ----------

__device__ __forceinline__ void gemm_body(
    char* LB, int m0, int n0, int tid,
    const float* __restrict__ x, const _Float16* __restrict__ Wc16,
    const float* __restrict__ bcat, _Float16* __restrict__ C) {
  _Float16 (*As)[LDP] = reinterpret_cast<_Float16(*)[LDP]>(LB);
  _Float16 (*Bs)[LDP] = reinterpret_cast<_Float16(*)[LDP]>(LB + BM * LDP * 2);
  const int lane = tid & 63;
  const int w = tid >> 6;
  const int wr = w >> 1, wc = w & 1;

  f32x4 acc[4][4];
#pragma unroll
  for (int m = 0; m < 4; ++m)
#pragma unroll
    for (int n = 0; n < 4; ++n) acc[m][n] = (f32x4){0.f, 0.f, 0.f, 0.f};

  const int arow_l = tid >> 4;        // 0..15
  const int acol   = (tid & 15) * 4;  // 0..60
  const int brow_l = tid >> 3;        // 0..31
  const int bcol   = (tid & 7) * 8;   // 0..56

  for (int k0 = 0; k0 < KP; k0 += BK) {
#pragma unroll
    for (int p = 0; p < 8; ++p) {
      int row = p * 16 + arow_l;
      int gk = k0 + acol;
      f32x4 v = (f32x4){0.f, 0.f, 0.f, 0.f};
      if (gk + 3 < NIN)  // 300 = 4*75: vectors never straddle the boundary
        v = *reinterpret_cast<const f32x4*>(&x[(size_t)(m0 + row) * NIN + gk]);
      f16x4 sv;
      sv[0] = (_Float16)v[0]; sv[1] = (_Float16)v[1];
      sv[2] = (_Float16)v[2]; sv[3] = (_Float16)v[3];
      *reinterpret_cast<f16x4*>(&As[row][acol]) = sv;
    }
#pragma unroll
    for (int p = 0; p < 4; ++p) {
      int n = p * 32 + brow_l;
      f16x8 v = *reinterpret_cast<const f16x8*>(&Wc16[(size_t)(n0 + n) * KP + k0 + bcol]);
      *reinterpret_cast<f16x8*>(&Bs[n][bcol]) = v;
    }
    __syncthreads();
#pragma unroll
    for (int ks = 0; ks < 2; ++ks) {
      const int kk = ks * 32 + (lane >> 4) * 8;
      f16x8 a[4], b[4];
#pragma unroll
      for (int m = 0; m < 4; ++m)
        a[m] = *reinterpret_cast<const f16x8*>(&As[wr * 64 + m * 16 + (lane & 15)][kk]);
#pragma unroll
      for (int n = 0; n < 4; ++n)
        b[n] = *reinterpret_cast<const f16x8*>(&Bs[wc * 64 + n * 16 + (lane & 15)][kk]);
#pragma unroll
      for (int m = 0; m < 4; ++m)
#pragma unroll
        for (int n = 0; n < 4; ++n)
          acc[m][n] = __builtin_amdgcn_mfma_f32_16x16x32_f16(a[m], b[n], acc[m][n], 0, 0, 0);
    }
    __syncthreads();
  }
  const int fc = lane & 15;
  const int fr = (lane >> 4) * 4;
#pragma unroll
  for (int n = 0; n < 4; ++n) {
    int col = n0 + wc * 64 + n * 16 + fc;
    float bias = bcat[col];
#pragma unroll
    for (int m = 0; m < 4; ++m) {
#pragma unroll
      for (int r = 0; r < 4; ++r) {
        int row = m0 + wr * 64 + m * 16 + fr + r;
        C[(size_t)row * NG + col] = (_Float16)(acc[m][n][r] + bias);
      }
    }
  }
}

__device__ __forceinline__ void decode_body(
    char* LB, int blk, int tid,
    const _Float16* __restrict__ hs, const float* __restrict__ Wdec,
    const float* __restrict__ bdec, float* __restrict__ out) {
  float* wl = reinterpret_cast<float*>(LB);          // 768 B
  float* bl = reinterpret_cast<float*>(LB + 768);    // 12 B
  float* ob = reinterpret_cast<float*>(LB + 784);    // 3072 B
  if (tid < NH * 3) wl[tid] = Wdec[tid];
  if (tid < 3) bl[tid] = bdec[tid];
  __syncthreads();
  const size_t idx = (size_t)blk * 256 + tid;
  const _Float16* hp = hs + idx * NH;
  float d0 = 0.f, d1 = 0.f, d2 = 0.f;
#pragma unroll
  for (int k = 0; k < NH; k += 8) {
    f16x8 h8 = *reinterpret_cast<const f16x8*>(&hp[k]);
#pragma unroll
    for (int j = 0; j < 8; ++j) {
      float hv = (float)h8[j];
      d0 += hv * wl[(k + j) * 3 + 0];
      d1 += hv * wl[(k + j) * 3 + 1];
      d2 += hv * wl[(k + j) * 3 + 2];
    }
  }
  ob[tid * 3 + 0] = d0 + bl[0];
  ob[tid * 3 + 1] = d1 + bl[1];
  ob[tid * 3 + 2] = d2 + bl[2];
  __syncthreads();
  if (tid < 192) {
    f32x4* o4 = reinterpret_cast<f32x4*>(out + (size_t)blk * 768);
    o4[tid] = reinterpret_cast<const f32x4*>(ob)[tid];
  }
}

// ---- rec-step macros: 2 active waves, lane = unit*2 + gate-pair -------------
// gp=0 lane owns gates {f,g}; gp=1 lane owns {i,o}. Pair exchange via DPP.
#define PAIR(v, j) __builtin_shufflevector(v, v, 2*(j), 2*(j)+1)
#define DOTW(KK) { f16x8 hv = hb[KK]; \
    aA0 = __builtin_amdgcn_fdot2(PAIR(hv,0), PAIR(wa##KK,0), aA0, false); \
    aB0 = __builtin_amdgcn_fdot2(PAIR(hv,0), PAIR(wb##KK,0), aB0, false); \
    aA1 = __builtin_amdgcn_fdot2(PAIR(hv,1), PAIR(wa##KK,1), aA1, false); \
    aB1 = __builtin_amdgcn_fdot2(PAIR(hv,1), PAIR(wb##KK,1), aB1, false); \
    aA0 = __builtin_amdgcn_fdot2(PAIR(hv,2), PAIR(wa##KK,2), aA0, false); \
    aB0 = __builtin_amdgcn_fdot2(PAIR(hv,2), PAIR(wb##KK,2), aB0, false); \
    aA1 = __builtin_amdgcn_fdot2(PAIR(hv,3), PAIR(wa##KK,3), aA1, false); \
    aB1 = __builtin_amdgcn_fdot2(PAIR(hv,3), PAIR(wb##KK,3), aB1, false); }

#define STEP2W(CA, CB, SP) { \
    float preA = (float)__builtin_bit_cast(_Float16, (unsigned short)(CA)); \
    float preB = (float)__builtin_bit_cast(_Float16, (unsigned short)(CB)); \
    const f16x8* hb = reinterpret_cast<const f16x8*>(hbuf + ((SP) & 1) * NH); \
    float aA0 = 0.f, aA1 = 0.f, aB0 = 0.f, aB1 = 0.f; \
    DOTW(0) DOTW(1) DOTW(2) DOTW(3) DOTW(4) DOTW(5) DOTW(6) DOTW(7) \
    preA += aA0 + aA1; preB += aB0 + aB1; \
    float xA = fminf(fmaxf(preA, -30.f), 30.f); \
    float sA = 1.f / (1.f + __expf(-xA));            /* f (gp0) or i (gp1) */ \
    float xB = fminf(fmaxf(preB, -clB), clB); \
    float yB = 1.f / (1.f + __expf(-mmB * xB)); \
    float actB = gp ? yB : (2.f * yB - 1.f);         /* g (gp0) or o (gp1) */ \
    float sAo = pair_swap(sA); \
    float aBo = pair_swap(actB); \
    float f_ = gp ? sAo : sA; \
    float g_ = gp ? aBo : actB; \
    float i_ = gp ? sA : sAo; \
    float o_ = gp ? actB : aBo; \
    float c1 = f_ * creg + i_ * g_;   /* both pair lanes, redundant */ \
    creg = c1; \
    float ct = fminf(fmaxf(c1, -15.f), 15.f); \
    float e2 = __expf(-2.f * ct); \
    float th = (1.f - e2) / (1.f + e2); \
    float h1 = o_ * th; \
    hreg = h1; \
    if (gp == 0) { \
      hbuf[(((SP) + 1) & 1) * NH + u] = (_Float16)h1; \
      *hp = (_Float16)h1;  /* fire-and-forget */ \
    } \
    hp += (size_t)BATCH * NH; \
    asm volatile("s_waitcnt lgkmcnt(0)" ::: "memory"); \
    __builtin_amdgcn_s_barrier(); }

// ---------------- standalone kernels (chunk 0 gemm, final decode) ------------

__global__ __launch_bounds__(256, 2) void gemm_i2h(
    const float* __restrict__ x, const _Float16* __restrict__ Wc16,
    const float* __restrict__ bcat, _Float16* __restrict__ C) {
  __shared__ __align__(16) char LB[36864];
  gemm_body(LB, blockIdx.y * BM, blockIdx.x * BN, threadIdx.x, x, Wc16, bcat, C);
}

__global__ __launch_bounds__(256) void decode(
    const _Float16* __restrict__ hs, const float* __restrict__ Wdec,
    const float* __restrict__ bdec, float* __restrict__ out) {
  __shared__ __align__(16) char LB[4096];
  decode_body(LB, blockIdx.x, threadIdx.x, hs, Wdec, bdec, out);
}

// ---------------- fused chunk kernel ----------------------------------------
// bid < 256            : rec for chunk k. TWO active waves (halves the per-step
//                        LDS broadcast-service: 16 vs 32 ds_read_b128 through
//                        the shared pipe); waves 2-3 stage weights then spin on
//                        matched barriers. Lane = unit*2 + gate-pair, DPP swap.
// bid < 256+512 (gemm) : i2h GEMM for chunk k+1 (rides in rec's shadow)
// rest (dec)           : decode of chunk k-1
__global__ __launch_bounds__(256, 2)
void fused_step(
    const _Float16* __restrict__ i2h_cur, _Float16* __restrict__ i2h_next,
    const float* __restrict__ x_next,
    const _Float16* __restrict__ Wc16, const float* __restrict__ bcat,
    const _Float16* __restrict__ Wg16,
    const float* __restrict__ h_in, const float* __restrict__ c_in,
    float* __restrict__ h_state, float* __restrict__ c_state,
    _Float16* __restrict__ hs_cur, const _Float16* __restrict__ hs_prev,
    const float* __restrict__ Wdec, const float* __restrict__ bdec,
    float* __restrict__ out_prev,
    float* __restrict__ hT_out, float* __restrict__ cT_out,
    int is_last, int has_gemm) {
  __shared__ __align__(16) char LB[36864];
  const int bid = blockIdx.x;
  const int tid = threadIdx.x;

  if (bid < BATCH) {
    // ------------------ rec role (2 active waves, T = TC) -------------------
    const int b = bid;
    const int wv = tid >> 6;
    const int l = tid & 63;
    const int gp = l & 1;                 // gate pair: 0={f,g}, 1={i,o}
    const int u = (wv & 1) * 32 + (l >> 1);
    const int colA = gp * 128 + u;        // f or i column
    const int colB = colA + 64;           // g or o column

    f16x8* Wst = reinterpret_cast<f16x8*>(LB);            // Wst[kk*256 + c]
    unsigned hoff = 0;
    asm volatile("" : "+s"(hoff));                        // opaque 0
    _Float16* hbuf = reinterpret_cast<_Float16*>(LB + hoff);  // [2][64]

    for (int e = tid; e < 8 * NG; e += 256) {
      int kk = e >> 8, c = e & 255;
      Wst[e] = *reinterpret_cast<const f16x8*>(Wg16 + (size_t)c * NH + kk * 8);
    }
    __syncthreads();

    // 16 named f16x8 (64 VGPR). hbuf writes go through the opaque base ->
    // may-alias all of LDS -> remat of these reads past the overwrite illegal.
#define LWA(KK) f16x8 wa##KK = Wst[(KK) * NG + colA];
#define LWB(KK) f16x8 wb##KK = Wst[(KK) * NG + colB];
    LWA(0) LWA(1) LWA(2) LWA(3) LWA(4) LWA(5) LWA(6) LWA(7)
    LWB(0) LWB(1) LWB(2) LWB(3) LWB(4) LWB(5) LWB(6) LWB(7)

    float creg = c_in[b * NH + u];        // replicated per pair, deterministic
    float hreg = 0.f;
    float h0v = (tid < NH) ? h_in[b * NH + tid] : 0.f;
    __syncthreads();   // all weight reads done before the overwrite below

    if (tid < NH) hbuf[tid] = (_Float16)h0v;   // clobbers weight region
    __syncthreads();

    if (wv < 2) {
      __builtin_amdgcn_s_setprio(1);
      const size_t st = (size_t)NG * BATCH;   // i2h f16 elems per step
      const unsigned short* ipA =
          reinterpret_cast<const unsigned short*>(i2h_cur) + (size_t)b * NG + colA;
      const unsigned short* ipB = ipA + 64;
      _Float16* hp = hs_cur + (size_t)b * NH + u;
      const float mmB = gp ? 1.f : 2.f;
      const float clB = gp ? 30.f : 15.f;

      int s = 0;
      {
        unsigned short c0a = ipA[0],      c0b = ipB[0];
        unsigned short c1a = ipA[st],     c1b = ipB[st];
        unsigned short c2a = ipA[2 * st], c2b = ipB[2 * st];
        unsigned short c3a = ipA[3 * st], c3b = ipB[3 * st];
        unsigned short n0a = ipA[4 * st], n0b = ipB[4 * st];
        unsigned short n1a = ipA[5 * st], n1b = ipB[5 * st];
        unsigned short n2a = ipA[6 * st], n2b = ipB[6 * st];
        unsigned short n3a = ipA[7 * st], n3b = ipB[7 * st];
        const unsigned short* ifA = ipA + 8 * st;
        const unsigned short* ifB = ipB + 8 * st;
        while (s + 4 <= TC) {
          unsigned short f0a = 0, f0b = 0, f1a = 0, f1b = 0;
          unsigned short f2a = 0, f2b = 0, f3a = 0, f3b = 0;
          if (s + 8  < TC) { f0a = ifA[0];      f0b = ifB[0]; }
          if (s + 9  < TC) { f1a = ifA[st];     f1b = ifB[st]; }
          if (s + 10 < TC) { f2a = ifA[2 * st]; f2b = ifB[2 * st]; }
          if (s + 11 < TC) { f3a = ifA[3 * st]; f3b = ifB[3 * st]; }
          ifA += 4 * st; ifB += 4 * st;
          STEP2W(c0a, c0b, s)
          STEP2W(c1a, c1b, s + 1)
          STEP2W(c2a, c2b, s + 2)
          STEP2W(c3a, c3b, s + 3)
          c0a = n0a; c0b = n0b; c1a = n1a; c1b = n1b;
          c2a = n2a; c2b = n2b; c3a = n3a; c3b = n3b;
          n0a = f0a; n0b = f0b; n1a = f1a; n1b = f1b;
          n2a = f2a; n2b = f2b; n3a = f3a; n3b = f3b;
          s += 4;
        }
      }
      __builtin_amdgcn_s_setprio(0);

      if (gp == 0) {
        h_state[b * NH + u] = hreg;
        c_state[b * NH + u] = creg;
        if (is_last) {
          hT_out[b * NH + u] = hreg;
          cT_out[b * NH + u] = creg;
        }
      }
    } else {
      // idle waves: matched barrier count (TC barriers, 4 per iteration)
      for (int s2 = 0; s2 + 4 <= TC; s2 += 4) {
        __builtin_amdgcn_s_barrier();
        __builtin_amdgcn_s_barrier();
        __builtin_amdgcn_s_barrier();
        __builtin_amdgcn_s_barrier();
      }
    }
  } else if (has_gemm && bid < BATCH + 2 * (TC * BATCH / BM)) {
    // ------------------ gemm role: i2h for chunk k+1 ------------------------
    const int gid = bid - BATCH;
    const int n0 = (gid & 1) * BN;      // N-pair adjacent -> x slab L2 reuse
    const int m0 = (gid >> 1) * BM;
    gemm_body(LB, m0, n0, tid, x_next, Wc16, bcat, i2h_next);
  } else {
    // ------------------ decode role: chunk k-1 ------------------------------
    const int did = bid - BATCH - (has_gemm ? 2 * (TC * BATCH / BM) : 0);
    decode_body(LB, did, tid, hs_prev, Wdec, bdec, out_prev);
  }
}

extern "C" void kernel_launch(void* const* d_in, const int* in_sizes, int n_in,
                              void* d_out, int out_size, void* d_ws, size_t ws_size,
                              hipStream_t stream) {
  const float* x    = (const float*)d_in[0];
  const float* h0   = (const float*)d_in[1];
  const float* c0   = (const float*)d_in[2];
  const float* Wpt0 = (const float*)d_in[3];
  const float* bpt0 = (const float*)d_in[4];
  const float* Wpt1 = (const float*)d_in[5];
  const float* bpt1 = (const float*)d_in[6];
  const float* Wglt = (const float*)d_in[7];
  const float* Wdec = (const float*)d_in[8];
  const float* bdec = (const float*)d_in[9];
  float* out = (float*)d_out;

  char* ws = (char*)d_ws;
  _Float16*  Wc16    = (_Float16*)(ws);           // 163840 B
  float*     bcat    = (float*)(ws + 163840);     // 1 KB
  _Float16*  Wg16    = (_Float16*)(ws + 164864);  // 32768 B (256 x 64 f16)
  float*     h_state = (float*)(ws + 197632);     // 64 KB
  float*     c_state = (float*)(ws + 263168);     // 64 KB
  const size_t base = 328704;

  const size_t chunk_i2h = (size_t)TC * BATCH * NG;     // f16 elems per chunk
  _Float16* i2h0 = (_Float16*)(ws + base);
  _Float16* i2h1 = i2h0 + chunk_i2h;
  _Float16* hs   = (_Float16*)(ws + base + 4 * chunk_i2h);  // 2 bufs * 2 B

  prep_w<<<dim3((NG * KP + 255) / 256), dim3(256), 0, stream>>>(
      Wpt0, bpt0, Wpt1, bpt1, Wglt, Wc16, bcat, Wg16);

  // chunk 0 GEMM (full GPU, nothing to overlap with yet)
  gemm_i2h<<<dim3(2, TC * BATCH / BM), dim3(256), 0, stream>>>(
      x, Wc16, bcat, i2h0);

  for (int k = 0; k < NCH; ++k) {
    _Float16* cur = (k & 1) ? i2h1 : i2h0;
    _Float16* nxt = (k & 1) ? i2h0 : i2h1;
    const int has_gemm = (k + 1 < NCH) ? 1 : 0;
    const int has_dec  = (k > 0) ? 1 : 0;
    const int nblk = BATCH + (has_gemm ? 2 * (TC * BATCH / BM) : 0)
                           + (has_dec ? (TC * BATCH / 256) : 0);
    const int kp = (k > 0) ? (k - 1) : 0;
    fused_step<<<dim3(nblk), dim3(256), 0, stream>>>(
        cur, nxt, x + (size_t)(k + 1) * TC * BATCH * NIN,
        Wc16, bcat, Wg16,
        (k == 0) ? h0 : h_state, (k == 0) ? c0 : c_state,
        h_state, c_state,
        hs + (size_t)k * TC * BATCH * NH,
        hs + (size_t)kp * TC * BATCH * NH,
        Wdec, bdec,
        out + (size_t)kp * TC * BATCH * 3,
        out + (size_t)SLEN * BATCH * 3,
        out + (size_t)SLEN * BATCH * 3 + BATCH * NH,
        (k == NCH - 1) ? 1 : 0, has_gemm);
  }

  // decode of the last chunk
  decode<<<dim3(TC * BATCH / 256), dim3(256), 0, stream>>>(
      hs + (size_t)(NCH - 1) * TC * BATCH * NH, Wdec, bdec,
      out + (size_t)(NCH - 1) * TC * BATCH * 3);
}

// Round 20
// 247.323 us; speedup vs baseline: 1.2460x; 1.2460x over previous
//
#include <hip/hip_runtime.h>
#include <hip/hip_bf16.h>

#define SLEN 512
#define BATCH 256
#define NIN 300
#define KP 320
#define NG 256
#define NH 64
#define BM 128
#define BN 128
#define BK 64
#define LDP 72   // padded LDS row length (f16) -> 144B rows, 2-way (free) b128 reads
#define TC 128   // steps per chunk
#define NCH (SLEN / TC)

typedef float f32x4 __attribute__((ext_vector_type(4)));
typedef _Float16 f16x8 __attribute__((ext_vector_type(8)));
typedef _Float16 f16x4 __attribute__((ext_vector_type(4)));

// quad-lane broadcast via DPP quad_perm [J,J,J,J] — VALU-speed cross-lane
template <int J>
__device__ __forceinline__ float quad_bcast(float v) {
  return __builtin_bit_cast(float,
      __builtin_amdgcn_mov_dpp(__builtin_bit_cast(int, v),
                               J * 0x55, 0xf, 0xf, true));
}

// Build Wc16[n][k] (f16, K padded to 320), bcat[n], and Wg16[col][k] = f16(W_glt[k][col]).
__global__ void prep_w(const float* __restrict__ Wpt0, const float* __restrict__ bpt0,
                       const float* __restrict__ Wpt1, const float* __restrict__ bpt1,
                       const float* __restrict__ Wglt,
                       _Float16* __restrict__ Wc16, float* __restrict__ bcat,
                       _Float16* __restrict__ Wg16) {
  int idx = blockIdx.x * 256 + threadIdx.x;
  if (idx < NG * KP) {
    int n = idx / KP, k = idx - n * KP;
    int g = n >> 6, h = n & 63;
    float w = 0.f;
    if (k < NIN) {
      if (h < 32) w = Wpt0[k * 128 + g * 32 + h];
      else        w = 0.5f * Wpt1[(k >> 1) * 128 + g * 32 + (h - 32)];
    }
    Wc16[idx] = (_Float16)w;
  }
  if (idx < NG * NH) {  // transpose W_glt (64 x 256) -> Wg16 (256 x 64), f16
    int c = idx >> 6, k = idx & 63;
    Wg16[idx] = (_Float16)Wglt[k * NG + c];
  }
  if (idx < NG) {
    int g = idx >> 6, h = idx & 63;
    bcat[idx] = (h < 32) ? bpt0[g * 32 + h] : bpt1[g * 32 + h - 32];
  }
}

// ---------------- shared device bodies (used by standalone + fused) ----------

__device__ __forceinline__ void gemm_body(
    char* LB, int m0, int n0, int tid,
    const float* __restrict__ x, const _Float16* __restrict__ Wc16,
    const float* __restrict__ bcat, _Float16* __restrict__ C) {
  _Float16 (*As)[LDP] = reinterpret_cast<_Float16(*)[LDP]>(LB);
  _Float16 (*Bs)[LDP] = reinterpret_cast<_Float16(*)[LDP]>(LB + BM * LDP * 2);
  const int lane = tid & 63;
  const int w = tid >> 6;
  const int wr = w >> 1, wc = w & 1;

  f32x4 acc[4][4];
#pragma unroll
  for (int m = 0; m < 4; ++m)
#pragma unroll
    for (int n = 0; n < 4; ++n) acc[m][n] = (f32x4){0.f, 0.f, 0.f, 0.f};

  const int arow_l = tid >> 4;        // 0..15
  const int acol   = (tid & 15) * 4;  // 0..60
  const int brow_l = tid >> 3;        // 0..31
  const int bcol   = (tid & 7) * 8;   // 0..56

  for (int k0 = 0; k0 < KP; k0 += BK) {
#pragma unroll
    for (int p = 0; p < 8; ++p) {
      int row = p * 16 + arow_l;
      int gk = k0 + acol;
      f32x4 v = (f32x4){0.f, 0.f, 0.f, 0.f};
      if (gk + 3 < NIN)  // 300 = 4*75: vectors never straddle the boundary
        v = *reinterpret_cast<const f32x4*>(&x[(size_t)(m0 + row) * NIN + gk]);
      f16x4 sv;
      sv[0] = (_Float16)v[0]; sv[1] = (_Float16)v[1];
      sv[2] = (_Float16)v[2]; sv[3] = (_Float16)v[3];
      *reinterpret_cast<f16x4*>(&As[row][acol]) = sv;
    }
#pragma unroll
    for (int p = 0; p < 4; ++p) {
      int n = p * 32 + brow_l;
      f16x8 v = *reinterpret_cast<const f16x8*>(&Wc16[(size_t)(n0 + n) * KP + k0 + bcol]);
      *reinterpret_cast<f16x8*>(&Bs[n][bcol]) = v;
    }
    __syncthreads();
#pragma unroll
    for (int ks = 0; ks < 2; ++ks) {
      const int kk = ks * 32 + (lane >> 4) * 8;
      f16x8 a[4], b[4];
#pragma unroll
      for (int m = 0; m < 4; ++m)
        a[m] = *reinterpret_cast<const f16x8*>(&As[wr * 64 + m * 16 + (lane & 15)][kk]);
#pragma unroll
      for (int n = 0; n < 4; ++n)
        b[n] = *reinterpret_cast<const f16x8*>(&Bs[wc * 64 + n * 16 + (lane & 15)][kk]);
#pragma unroll
      for (int m = 0; m < 4; ++m)
#pragma unroll
        for (int n = 0; n < 4; ++n)
          acc[m][n] = __builtin_amdgcn_mfma_f32_16x16x32_f16(a[m], b[n], acc[m][n], 0, 0, 0);
    }
    __syncthreads();
  }
  const int fc = lane & 15;
  const int fr = (lane >> 4) * 4;
#pragma unroll
  for (int n = 0; n < 4; ++n) {
    int col = n0 + wc * 64 + n * 16 + fc;
    float bias = bcat[col];
#pragma unroll
    for (int m = 0; m < 4; ++m) {
#pragma unroll
      for (int r = 0; r < 4; ++r) {
        int row = m0 + wr * 64 + m * 16 + fr + r;
        C[(size_t)row * NG + col] = (_Float16)(acc[m][n][r] + bias);
      }
    }
  }
}

__device__ __forceinline__ void decode_body(
    char* LB, int blk, int tid,
    const _Float16* __restrict__ hs, const float* __restrict__ Wdec,
    const float* __restrict__ bdec, float* __restrict__ out) {
  float* wl = reinterpret_cast<float*>(LB);          // 768 B
  float* bl = reinterpret_cast<float*>(LB + 768);    // 12 B
  float* ob = reinterpret_cast<float*>(LB + 784);    // 3072 B
  if (tid < NH * 3) wl[tid] = Wdec[tid];
  if (tid < 3) bl[tid] = bdec[tid];
  __syncthreads();
  const size_t idx = (size_t)blk * 256 + tid;
  const _Float16* hp = hs + idx * NH;
  float d0 = 0.f, d1 = 0.f, d2 = 0.f;
#pragma unroll
  for (int k = 0; k < NH; k += 8) {
    f16x8 h8 = *reinterpret_cast<const f16x8*>(&hp[k]);
#pragma unroll
    for (int j = 0; j < 8; ++j) {
      float hv = (float)h8[j];
      d0 += hv * wl[(k + j) * 3 + 0];
      d1 += hv * wl[(k + j) * 3 + 1];
      d2 += hv * wl[(k + j) * 3 + 2];
    }
  }
  ob[tid * 3 + 0] = d0 + bl[0];
  ob[tid * 3 + 1] = d1 + bl[1];
  ob[tid * 3 + 2] = d2 + bl[2];
  __syncthreads();
  if (tid < 192) {
    f32x4* o4 = reinterpret_cast<f32x4*>(out + (size_t)blk * 768);
    o4[tid] = reinterpret_cast<const f32x4*>(ob)[tid];
  }
}

// rec-step macros: quad-layout (lane = unit*4 + gate), DPP gate exchange
#define PAIR(v, j) __builtin_shufflevector(v, v, 2*(j), 2*(j)+1)
#define DOT(hb, i, W) { f16x8 hv = (hb)[i]; \
      acc0 = __builtin_amdgcn_fdot2(PAIR(hv,0), PAIR(W,0), acc0, false); \
      acc1 = __builtin_amdgcn_fdot2(PAIR(hv,1), PAIR(W,1), acc1, false); \
      acc0 = __builtin_amdgcn_fdot2(PAIR(hv,2), PAIR(W,2), acc0, false); \
      acc1 = __builtin_amdgcn_fdot2(PAIR(hv,3), PAIR(W,3), acc1, false); }

#define STEP(CUR, SP) { \
    float cur_ = (float)__builtin_bit_cast(_Float16, (unsigned short)(CUR)); \
    const f16x8* hb = reinterpret_cast<const f16x8*>(hbuf + ((SP) & 1) * NH); \
    float acc0 = 0.f, acc1 = 0.f; \
    DOT(hb, 0, w0) DOT(hb, 1, w1) DOT(hb, 2, w2) DOT(hb, 3, w3) \
    DOT(hb, 4, w4) DOT(hb, 5, w5) DOT(hb, 6, w6) DOT(hb, 7, w7) \
    float pre = cur_ + (acc0 + acc1); \
    float xx = fminf(fmaxf(pre, -30.f), 30.f); \
    float e = __expf(-mm * xx); \
    float y = 1.f / (1.f + e); \
    float act = (qid == 1) ? (2.f * y - 1.f) : y; \
    float f_ = quad_bcast<0>(act); \
    float g_ = quad_bcast<1>(act); \
    float i_ = quad_bcast<2>(act); \
    float o_ = quad_bcast<3>(act); \
    float c1 = f_ * creg + i_ * g_;   /* all 4 quad lanes, redundant */ \
    creg = c1; \
    float ct = fminf(fmaxf(c1, -15.f), 15.f); \
    float e2 = __expf(-2.f * ct); \
    float th = (1.f - e2) / (1.f + e2); \
    float h1 = o_ * th; \
    hreg = h1; \
    if (qid == 0) { \
      hbuf[(((SP) + 1) & 1) * NH + unit] = (_Float16)h1; \
      *hp = (_Float16)h1;  /* fire-and-forget */ \
    } \
    hp += st >> 2; /* BATCH*NH f16 per step */ \
    asm volatile("s_waitcnt lgkmcnt(0)" ::: "memory"); \
    __builtin_amdgcn_s_barrier(); }

// ---------------- standalone kernels (chunk 0 gemm, final decode) ------------

__global__ __launch_bounds__(256, 2) void gemm_i2h(
    const float* __restrict__ x, const _Float16* __restrict__ Wc16,
    const float* __restrict__ bcat, _Float16* __restrict__ C) {
  __shared__ __align__(16) char LB[36864];
  gemm_body(LB, blockIdx.y * BM, blockIdx.x * BN, threadIdx.x, x, Wc16, bcat, C);
}

__global__ __launch_bounds__(256) void decode(
    const _Float16* __restrict__ hs, const float* __restrict__ Wdec,
    const float* __restrict__ bdec, float* __restrict__ out) {
  __shared__ __align__(16) char LB[4096];
  decode_body(LB, blockIdx.x, threadIdx.x, hs, Wdec, bdec, out);
}

// ---------------- fused chunk kernel ----------------------------------------
// bid < 256            : rec for chunk k (quad-layout, 1 block/row, 4 waves)
//                        at s_setprio(1) (null measured, harmless).
// bid < 256+512 (gemm) : i2h GEMM for chunk k+1 (prio 0, rides in rec shadow)
// rest (dec)           : decode of chunk k-1
__global__ __launch_bounds__(256, 2)
void fused_step(
    const _Float16* __restrict__ i2h_cur, _Float16* __restrict__ i2h_next,
    const float* __restrict__ x_next,
    const _Float16* __restrict__ Wc16, const float* __restrict__ bcat,
    const _Float16* __restrict__ Wg16,
    const float* __restrict__ h_in, const float* __restrict__ c_in,
    float* __restrict__ h_state, float* __restrict__ c_state,
    _Float16* __restrict__ hs_cur, const _Float16* __restrict__ hs_prev,
    const float* __restrict__ Wdec, const float* __restrict__ bdec,
    float* __restrict__ out_prev,
    float* __restrict__ hT_out, float* __restrict__ cT_out,
    int is_last, int has_gemm) {
  __shared__ __align__(16) char LB[36864];
  const int bid = blockIdx.x;
  const int tid = threadIdx.x;

  if (bid < BATCH) {
    // ------------------ rec role (quad layout, T = TC) ----------------------
    const int b = bid;
    const int ww = tid >> 6;
    const int l = tid & 63;
    const int qid = l & 3;              // gate index within quad
    const int unit = ww * 16 + (l >> 2);
    const int col = qid * 64 + unit;    // gate column in [0,256)

    f16x8* Wst = reinterpret_cast<f16x8*>(LB);           // Wst[kk*256 + c]
    _Float16* hbuf = reinterpret_cast<_Float16*>(LB);    // hbuf[(s&1)*64 + u]

    for (int e = tid; e < 8 * NG; e += 256) {
      int kk = e >> 8, c = e & 255;
      Wst[e] = *reinterpret_cast<const f16x8*>(Wg16 + (size_t)c * NH + kk * 8);
    }
    __syncthreads();

    f16x8 w0 = Wst[0 * NG + col], w1 = Wst[1 * NG + col];
    f16x8 w2 = Wst[2 * NG + col], w3 = Wst[3 * NG + col];
    f16x8 w4 = Wst[4 * NG + col], w5 = Wst[5 * NG + col];
    f16x8 w6 = Wst[6 * NG + col], w7 = Wst[7 * NG + col];

    float creg = c_in[b * NH + unit];   // replicated per quad, deterministic
    float hreg = 0.f;
    float h0v = (tid < NH) ? h_in[b * NH + tid] : 0.f;
    __syncthreads();   // all weight reads done before the overwrite below

    if (tid < NH) hbuf[tid] = (_Float16)h0v;   // clobbers weight region
    __syncthreads();

    __builtin_amdgcn_s_setprio(1);      // rec = critical chain

    const size_t st = (size_t)NG * BATCH;      // i2h f16 elems per step
    const unsigned short* ip =
        reinterpret_cast<const unsigned short*>(i2h_cur) + (size_t)b * NG + col;
    _Float16* hp = hs_cur + (size_t)b * NH + unit;
    const float mm = (qid == 1) ? 2.f : 1.f;

    int s = 0;
    {
      unsigned short c0v = ip[0],      c1v = ip[st],     c2v = ip[2 * st], c3v = ip[3 * st];
      unsigned short n0v = ip[4 * st], n1v = ip[5 * st], n2v = ip[6 * st], n3v = ip[7 * st];
      const unsigned short* ipf = ip + 8 * st;
      while (s + 4 <= TC) {
        unsigned short f0v = 0, f1v = 0, f2v = 0, f3v = 0;
        if (s + 8  < TC) f0v = ipf[0];        // uniform branch; nothing reads
        if (s + 9  < TC) f1v = ipf[st];       // the reg until STEP next quad
        if (s + 10 < TC) f2v = ipf[2 * st];
        if (s + 11 < TC) f3v = ipf[3 * st];
        ipf += 4 * st;
        STEP(c0v, s)
        STEP(c1v, s + 1)
        STEP(c2v, s + 2)
        STEP(c3v, s + 3)
        c0v = n0v; c1v = n1v; c2v = n2v; c3v = n3v;   // waits: loads 1 quad old
        n0v = f0v; n1v = f1v; n2v = f2v; n3v = f3v;   // waits: loads this quad top
        s += 4;
      }
    }
    __builtin_amdgcn_s_setprio(0);

    if (qid == 0) {
      h_state[b * NH + unit] = hreg;
      c_state[b * NH + unit] = creg;
      if (is_last) {
        hT_out[b * NH + unit] = hreg;
        cT_out[b * NH + unit] = creg;
      }
    }
  } else if (has_gemm && bid < BATCH + 2 * (TC * BATCH / BM)) {
    // ------------------ gemm role: i2h for chunk k+1 ------------------------
    const int gid = bid - BATCH;
    const int n0 = (gid & 1) * BN;      // N-pair adjacent -> x slab L2 reuse
    const int m0 = (gid >> 1) * BM;
    gemm_body(LB, m0, n0, tid, x_next, Wc16, bcat, i2h_next);
  } else {
    // ------------------ decode role: chunk k-1 ------------------------------
    const int did = bid - BATCH - (has_gemm ? 2 * (TC * BATCH / BM) : 0);
    decode_body(LB, did, tid, hs_prev, Wdec, bdec, out_prev);
  }
}

extern "C" void kernel_launch(void* const* d_in, const int* in_sizes, int n_in,
                              void* d_out, int out_size, void* d_ws, size_t ws_size,
                              hipStream_t stream) {
  const float* x    = (const float*)d_in[0];
  const float* h0   = (const float*)d_in[1];
  const float* c0   = (const float*)d_in[2];
  const float* Wpt0 = (const float*)d_in[3];
  const float* bpt0 = (const float*)d_in[4];
  const float* Wpt1 = (const float*)d_in[5];
  const float* bpt1 = (const float*)d_in[6];
  const float* Wglt = (const float*)d_in[7];
  const float* Wdec = (const float*)d_in[8];
  const float* bdec = (const float*)d_in[9];
  float* out = (float*)d_out;

  char* ws = (char*)d_ws;
  _Float16*  Wc16    = (_Float16*)(ws);           // 163840 B
  float*     bcat    = (float*)(ws + 163840);     // 1 KB
  _Float16*  Wg16    = (_Float16*)(ws + 164864);  // 32768 B (256 x 64 f16)
  float*     h_state = (float*)(ws + 197632);     // 64 KB
  float*     c_state = (float*)(ws + 263168);     // 64 KB
  const size_t base = 328704;

  const size_t chunk_i2h = (size_t)TC * BATCH * NG;     // f16 elems per chunk
  _Float16* i2h0 = (_Float16*)(ws + base);
  _Float16* i2h1 = i2h0 + chunk_i2h;
  _Float16* hs   = (_Float16*)(ws + base + 4 * chunk_i2h);  // 2 bufs * 2 B

  prep_w<<<dim3((NG * KP + 255) / 256), dim3(256), 0, stream>>>(
      Wpt0, bpt0, Wpt1, bpt1, Wglt, Wc16, bcat, Wg16);

  // chunk 0 GEMM (full GPU, nothing to overlap with yet)
  gemm_i2h<<<dim3(2, TC * BATCH / BM), dim3(256), 0, stream>>>(
      x, Wc16, bcat, i2h0);

  for (int k = 0; k < NCH; ++k) {
    _Float16* cur = (k & 1) ? i2h1 : i2h0;
    _Float16* nxt = (k & 1) ? i2h0 : i2h1;
    const int has_gemm = (k + 1 < NCH) ? 1 : 0;
    const int has_dec  = (k > 0) ? 1 : 0;
    const int nblk = BATCH + (has_gemm ? 2 * (TC * BATCH / BM) : 0)
                           + (has_dec ? (TC * BATCH / 256) : 0);
    const int kp = (k > 0) ? (k - 1) : 0;
    fused_step<<<dim3(nblk), dim3(256), 0, stream>>>(
        cur, nxt, x + (size_t)(k + 1) * TC * BATCH * NIN,
        Wc16, bcat, Wg16,
        (k == 0) ? h0 : h_state, (k == 0) ? c0 : c_state,
        h_state, c_state,
        hs + (size_t)k * TC * BATCH * NH,
        hs + (size_t)kp * TC * BATCH * NH,
        Wdec, bdec,
        out + (size_t)kp * TC * BATCH * 3,
        out + (size_t)SLEN * BATCH * 3,
        out + (size_t)SLEN * BATCH * 3 + BATCH * NH,
        (k == NCH - 1) ? 1 : 0, has_gemm);
  }

  // decode of the last chunk
  decode<<<dim3(TC * BATCH / 256), dim3(256), 0, stream>>>(
      hs + (size_t)(NCH - 1) * TC * BATCH * NH, Wdec, bdec,
      out + (size_t)(NCH - 1) * TC * BATCH * 3);
}